// Round 20
// baseline (179.850 us; speedup 1.0000x reference)
//
#include <hip/hip_runtime.h>
#include <stdint.h>

typedef unsigned short u16;
typedef unsigned int u32;
typedef u16 u16x8 __attribute__((ext_vector_type(8)));
typedef __bf16 bf16x8 __attribute__((ext_vector_type(8)));
typedef float f32x4 __attribute__((ext_vector_type(4)));

#define S_LEN 1374
#define S_PAD 1408
#define PRE_TOK 5
#define HID 768
#define NH 12
#define MPAD 11008

__device__ __forceinline__ u16 f2bf(float f) {
    union { float f; u32 u; } v; v.f = f;
    u32 r = v.u + 0x7fffu + ((v.u >> 16) & 1u);
    return (u16)(r >> 16);
}
__device__ __forceinline__ bf16x8 as_bf(u16x8 v) { bf16x8 r; __builtin_memcpy(&r, &v, 16); return r; }
__device__ __forceinline__ bf16x8 lds_load8(const u16* p) {
    u16x8 t = *(const u16x8*)p;
    return as_bf(t);
}
__device__ __forceinline__ u32 cvtpk_bf16(float lo, float hi) {
    u32 r;
    asm("v_cvt_pk_bf16_f32 %0, %1, %2" : "=v"(r) : "v"(lo), "v"(hi));
    return r;
}
// raw v_exp_f32: 1 instr. Valid here: inputs in (-1e30, ~+8]; v_exp(-1e30)=0.
__device__ __forceinline__ float fexp2(float x) {
    float r;
    asm("v_exp_f32 %0, %1" : "=v"(r) : "v"(x));
    return r;
}
// async global->LDS, 16B per lane. LDS dest = wave-uniform base + lane*16.
__device__ __forceinline__ void gload16(void* lds, const void* g) {
    unsigned int __attribute__((address_space(1)))* gp =
        (unsigned int __attribute__((address_space(1)))*)(unsigned long long)g;
    unsigned int __attribute__((address_space(3)))* lp =
        (unsigned int __attribute__((address_space(3)))*)(unsigned int)(unsigned long long)lds;
    __builtin_amdgcn_global_load_lds(gp, lp, 16, 0, 0);
}
// bijective XCD-chunk swizzle (m204): contiguous logical spans per XCD.
__device__ __forceinline__ int xcd_swz(int orig, int nwg) {
    int qd = nwg >> 3, rd = nwg & 7;
    int xcd = orig & 7, rem = orig >> 3;
    return (xcd < rd ? xcd * (qd + 1) : rd * (qd + 1) + (xcd - rd) * qd) + rem;
}

// ---------------- fused pack kernel (pack_x + pack_w in one launch) ----------------

__global__ __launch_bounds__(256) void pack_xw(
    const float* __restrict__ X, const float* __restrict__ Wq, const float* __restrict__ Wk,
    const float* __restrict__ Wv, const float* __restrict__ Wp, const float* __restrict__ bq,
    const float* __restrict__ bv, u16* __restrict__ Xb,
    u16* __restrict__ wqkv, u16* __restrict__ wpb, float* __restrict__ bqkv)
{
    int bid = blockIdx.x;
    int tid = threadIdx.x;
    if (bid < 4128) {
        size_t i = (size_t)bid * 256 + tid;
        size_t e = i * 8;
        const size_t TOT = (size_t)10992 * HID;
        u16x8 o = {0,0,0,0,0,0,0,0};
        if (e < TOT) {
            f32x4 a = *(const f32x4*)(X + e);
            f32x4 b = *(const f32x4*)(X + e + 4);
#pragma unroll
            for (int j = 0; j < 4; ++j) { o[j] = f2bf(a[j]); o[4 + j] = f2bf(b[j]); }
        }
        *(u16x8*)(Xb + e) = o;
        return;
    }
    int g = (bid - 4128) * 256 + tid;
    const int QKV8 = 2304 * HID / 8;   // 221184
    const int P8 = HID * HID / 8;      // 73728
    if (g < QKV8) {
        int e = g * 8;
        int row = e / HID, col = e - row * HID;
        const float* src = (row < 768) ? (Wq + (size_t)row * HID + col)
                         : (row < 1536) ? (Wk + (size_t)(row - 768) * HID + col)
                                        : (Wv + (size_t)(row - 1536) * HID + col);
        u16x8 o;
#pragma unroll
        for (int j = 0; j < 8; ++j) o[j] = f2bf(src[j]);
        *(u16x8*)(wqkv + e) = o;
    } else if (g < QKV8 + P8) {
        int e = (g - QKV8) * 8;
        u16x8 o;
#pragma unroll
        for (int j = 0; j < 8; ++j) o[j] = f2bf(Wp[e + j]);
        *(u16x8*)(wpb + e) = o;
    }
    if (g < 288) {
        int e = g * 8;
#pragma unroll
        for (int j = 0; j < 8; ++j) {
            int c = e + j;
            bqkv[c] = (c < 768) ? bq[c] : (c < 1536 ? 0.f : bv[c - 1536]);
        }
    }
}

// ---------------- QKV GEMM (R20: 256x256 tile, 16 waves, 2-barrier) ----------------
// Per-wave code identical to the proven 128x256 kernel (same 64x64 sub-tile,
// acc[4][4], fragment reads, ^((r&7)<<4) swizzle). Geometry: 16 waves (4M x
// 4N), LDS 64 KB (As+Bs 32 KB each, 2 blocks/CU LDS-fit), staging 2 sweeps x
// 16 KB per tensor, grid 9 x 43 = 387. Staged bytes/output 1.5 -> 1.0 and
// barriers/element halved vs 128x256 (the R15 lever, extrapolated).
// Fused epilogue: Q: bias+RoPE+QSCALE -> Qh; K: RoPE -> Kh; V: bias -> Yv.

__global__ __launch_bounds__(1024) void gemm_qkv256(
    const u16* __restrict__ A, const u16* __restrict__ B, const float* __restrict__ bias,
    u16* __restrict__ Qh, u16* __restrict__ Kh, u16* __restrict__ Yv,
    const float* __restrict__ SN, const float* __restrict__ CS, int K)
{
    __shared__ u16 As[256 * 64];   // 32 KB
    __shared__ u16 Bs[256 * 64];   // 32 KB
    int tid = threadIdx.x;          // 0..1023
    int w = tid >> 6, l = tid & 63; // 16 waves
    int fr = l & 15, fg = l >> 4;
    int wg = xcd_swz(blockIdx.x, 387);
    int col0 = (wg % 9) * 256;
    int row0 = (wg / 9) * 256;
    int wr = (w >> 2) * 64;         // 4 M-waves
    int wc = (w & 3) * 64;          // 4 N-waves

    f32x4 zero4 = {0.f, 0.f, 0.f, 0.f};
    f32x4 acc[4][4];
#pragma unroll
    for (int m = 0; m < 4; ++m)
#pragma unroll
        for (int n = 0; n < 4; ++n) acc[m][n] = zero4;

    // staging maps: 1024 thr x 16B = 16 KB/sweep; 2 sweeps per tensor.
    int srow[2], soff[2];
#pragma unroll
    for (int i = 0; i < 2; ++i) {
        int sbyte = (i * 1024 + tid) * 16;
        int r = sbyte >> 7;
        int ir = (sbyte & 127) ^ ((r & 7) << 4);
        srow[i] = r; soff[i] = ir >> 1;
    }

    for (int kt = 0; kt < K; kt += 64) {
#pragma unroll
        for (int i = 0; i < 2; ++i) {
            gload16((char*)As + i * 16384 + w * 1024,
                    A + (size_t)(row0 + srow[i]) * K + kt + soff[i]);
            gload16((char*)Bs + i * 16384 + w * 1024,
                    B + (size_t)(col0 + srow[i]) * K + kt + soff[i]);
        }
        __syncthreads();
#pragma unroll
        for (int c = 0; c < 2; ++c) {
            bf16x8 af[4], bfr[4];
#pragma unroll
            for (int m = 0; m < 4; ++m) {
                int r = wr + m * 16 + fr;
                int byte_ = (c * 64 + fg * 16) ^ ((r & 7) << 4);
                af[m] = lds_load8(As + r * 64 + (byte_ >> 1));
            }
#pragma unroll
            for (int n = 0; n < 4; ++n) {
                int r = wc + n * 16 + fr;
                int byte_ = (c * 64 + fg * 16) ^ ((r & 7) << 4);
                bfr[n] = lds_load8(Bs + r * 64 + (byte_ >> 1));
            }
#pragma unroll
            for (int m = 0; m < 4; ++m)
#pragma unroll
                for (int n = 0; n < 4; ++n)
                    acc[m][n] = __builtin_amdgcn_mfma_f32_16x16x32_bf16(af[m], bfr[n], acc[m][n], 0, 0, 0);
        }
        __syncthreads();
    }

    int sect = col0 >= 1536 ? 2 : (col0 >= 768 ? 1 : 0);
    if (sect == 2) {
#pragma unroll
        for (int m = 0; m < 4; ++m)
#pragma unroll
            for (int n = 0; n < 4; ++n) {
                int gn = col0 + wc + n * 16 + fr;
                float bvv = bias[gn];
#pragma unroll
                for (int j = 0; j < 4; ++j) {
                    int gm = row0 + wr + m * 16 + fg * 4 + j;
                    if (gm < 10992)
                        Yv[(size_t)gm * HID + (gn - 1536)] = f2bf(acc[m][n][j] + bvv);
                }
            }
    } else {
        u16* H = sect ? Kh : Qh;
        const float QS = sect ? 1.f : 0.125f * 1.44269504088896f;   // exp2-domain Q scale
        int hh = ((col0 + wc) >> 6) - sect * NH;                    // head 0..11
        float bv4[4];
#pragma unroll
        for (int n = 0; n < 4; ++n) bv4[n] = bias[col0 + wc + n * 16 + fr];
#pragma unroll
        for (int m = 0; m < 4; ++m)
#pragma unroll
            for (int j = 0; j < 4; ++j) {
                int gm = row0 + wr + m * 16 + fg * 4 + j;
                if (gm < 10992) {
                    int b = gm / 1374, s = gm - b * 1374;
                    size_t ob = ((size_t)(b * NH + hh) * S_PAD + s) * 64;
#pragma unroll
                    for (int n2 = 0; n2 < 2; ++n2) {
                        int d = n2 * 16 + fr;
                        float v1 = acc[m][n2][j] + bv4[n2];
                        float v2 = acc[m][n2 + 2][j] + bv4[n2 + 2];
                        float a1 = v1, a2 = v2;
                        if (s >= PRE_TOK) {
                            size_t rr = (size_t)(s - PRE_TOK) * 64;
                            float c1 = CS[rr + d], s1 = SN[rr + d];
                            float c2 = CS[rr + d + 32], s2 = SN[rr + d + 32];
                            a1 = v1 * c1 - v2 * s1;
                            a2 = v2 * c2 + v1 * s2;
                        }
                        H[ob + d]      = f2bf(a1 * QS);
                        H[ob + d + 32] = f2bf(a2 * QS);
                    }
                }
            }
    }
}

// ---------------- proj GEMM (unchanged best: 128x256 tile, 8 waves) ----------------

__global__ __launch_bounds__(512) void gemm_proj(
    const u16* __restrict__ A, const u16* __restrict__ B, const float* __restrict__ bias,
    float* __restrict__ Yf, int N, int K, int nx, int nwg)
{
    __shared__ u16 As[128 * 64];   // 16 KB
    __shared__ u16 Bs[256 * 64];   // 32 KB
    int tid = threadIdx.x;          // 0..511
    int w = tid >> 6, l = tid & 63; // 8 waves
    int fr = l & 15, fg = l >> 4;
    int wg = xcd_swz(blockIdx.x, nwg);
    int col0 = (wg % nx) * 256;
    int row0 = (wg / nx) * 128;
    int wr = (w >> 2) * 64;
    int wc = (w & 3) * 64;

    f32x4 zero4 = {0.f, 0.f, 0.f, 0.f};
    f32x4 acc[4][4];
#pragma unroll
    for (int m = 0; m < 4; ++m)
#pragma unroll
        for (int n = 0; n < 4; ++n) acc[m][n] = zero4;

    int arow[2], aoff[2];
#pragma unroll
    for (int i = 0; i < 2; ++i) {
        int sbyte = (i * 512 + tid) * 16;
        int r = sbyte >> 7;
        int ir = (sbyte & 127) ^ ((r & 7) << 4);
        arow[i] = r; aoff[i] = ir >> 1;
    }
    int brow[4], boff[4];
#pragma unroll
    for (int i = 0; i < 4; ++i) {
        int sbyte = (i * 512 + tid) * 16;
        int r = sbyte >> 7;
        int ir = (sbyte & 127) ^ ((r & 7) << 4);
        brow[i] = r; boff[i] = ir >> 1;
    }

    for (int kt = 0; kt < K; kt += 64) {
#pragma unroll
        for (int i = 0; i < 2; ++i)
            gload16((char*)As + i * 8192 + w * 1024,
                    A + (size_t)(row0 + arow[i]) * K + kt + aoff[i]);
#pragma unroll
        for (int i = 0; i < 4; ++i)
            gload16((char*)Bs + i * 8192 + w * 1024,
                    B + (size_t)(col0 + brow[i]) * K + kt + boff[i]);
        __syncthreads();
#pragma unroll
        for (int c = 0; c < 2; ++c) {
            bf16x8 af[4], bfr[4];
#pragma unroll
            for (int m = 0; m < 4; ++m) {
                int r = wr + m * 16 + fr;
                int byte_ = (c * 64 + fg * 16) ^ ((r & 7) << 4);
                af[m] = lds_load8(As + r * 64 + (byte_ >> 1));
            }
#pragma unroll
            for (int n = 0; n < 4; ++n) {
                int r = wc + n * 16 + fr;
                int byte_ = (c * 64 + fg * 16) ^ ((r & 7) << 4);
                bfr[n] = lds_load8(Bs + r * 64 + (byte_ >> 1));
            }
#pragma unroll
            for (int m = 0; m < 4; ++m)
#pragma unroll
                for (int n = 0; n < 4; ++n)
                    acc[m][n] = __builtin_amdgcn_mfma_f32_16x16x32_bf16(af[m], bfr[n], acc[m][n], 0, 0, 0);
        }
        __syncthreads();
    }

#pragma unroll
    for (int m = 0; m < 4; ++m)
#pragma unroll
        for (int n = 0; n < 4; ++n) {
            int gn = col0 + wc + n * 16 + fr;
            float bvv = bias[gn];
#pragma unroll
            for (int j = 0; j < 4; ++j) {
                int gm = row0 + wr + m * 16 + fg * 4 + j;
                if (gm < 10992) Yf[(size_t)gm * N + gn] = acc[m][n][j] + bvv;
            }
        }
}

// ---------------- V head-transpose: Yv[token][768] -> Vt[bh][64][S_PAD] ----------------

__global__ __launch_bounds__(256) void v_pack(const u16* __restrict__ Yv, u16* __restrict__ Vt) {
    int st = blockIdx.x, bh = blockIdx.y;
    int b = bh / NH, h = bh - b * NH;
    int tid = threadIdx.x;
    int sl = tid >> 2, dg = (tid & 3) * 8;
    int s = st * 64 + sl;
    __shared__ u16 vtile[64 * 64];

    u16x8 a = {0,0,0,0,0,0,0,0}, a2 = {0,0,0,0,0,0,0,0};
    if (s < S_LEN) {
        size_t base = ((size_t)b * S_LEN + s) * HID + h * 64;
        a  = *(const u16x8*)(Yv + base + dg);
        a2 = *(const u16x8*)(Yv + base + 32 + dg);
    }
#pragma unroll
    for (int j = 0; j < 8; ++j) {
        vtile[(dg + j) * 64 + sl] = a[j];
        vtile[(32 + dg + j) * 64 + sl] = a2[j];
    }
    __syncthreads();
    int d = tid >> 2, so = (tid & 3) * 8;
    u16x8 ov0 = *(const u16x8*)(vtile + d * 64 + so);
    u16x8 ov1 = *(const u16x8*)(vtile + d * 64 + so + 32);
    size_t vrow = ((size_t)bh * 64 + d) * S_PAD + st * 64;
    *(u16x8*)(Vt + vrow + so) = ov0;
    *(u16x8*)(Vt + vrow + so + 32) = ov1;
}

// ---------------- flash attention (KVBLK=64, two 32-key sub-phases/barrier) ----

#define FLASH_B64(Kc, Vc, KsN, VsN, ktn, DO_STAGE, DO_MASK)                           \
    {                                                                                 \
        asm volatile("s_waitcnt vmcnt(0) lgkmcnt(0)" ::: "memory");                   \
        __syncthreads();                                                              \
        if (DO_STAGE) {                                                               \
            int k0n = (ktn) * 64;                                                     \
            _Pragma("unroll")                                                         \
            for (int i = 0; i < 2; ++i) {                                             \
                gload16((char*)(KsN) + i * 4096 + w * 1024, Kb + (size_t)k0n * 64 + kfix[i]); \
                gload16((char*)(VsN) + i * 4096 + w * 1024, Vb + (size_t)k0n + vfix[i]);      \
            }                                                                         \
        }                                                                             \
        _Pragma("unroll")                                                             \
        for (int h = 0; h < 2; ++h) {                                                 \
            f32x4 sf[2][2];                                                           \
            __builtin_amdgcn_s_setprio(1);                                            \
            _Pragma("unroll")                                                         \
            for (int n = 0; n < 2; ++n) {                                             \
                f32x4 q0a = zero4, q1a = zero4;                                       \
                _Pragma("unroll")                                                     \
                for (int c = 0; c < 2; ++c) {                                         \
                    int byte_ = (c * 64 + fg * 16) ^ ((fr & 7) << 4);                 \
                    bf16x8 kf = lds_load8((Kc) + (h * 32 + n * 16 + fr) * 64 + (byte_ >> 1)); \
                    q0a = __builtin_amdgcn_mfma_f32_16x16x32_bf16(kf, qf[0][c], q0a, 0, 0, 0); \
                    q1a = __builtin_amdgcn_mfma_f32_16x16x32_bf16(kf, qf[1][c], q1a, 0, 0, 0); \
                }                                                                     \
                sf[0][n] = q0a; sf[1][n] = q1a;                                       \
            }                                                                         \
            __builtin_amdgcn_s_setprio(0);                                            \
            if (DO_MASK) {                                                            \
                _Pragma("unroll")                                                     \
                for (int n = 0; n < 2; ++n)                                           \
                    _Pragma("unroll")                                                 \
                    for (int j = 0; j < 4; ++j)                                       \
                        if (1344 + h * 32 + 8 * fg + 4 * n + j >= S_LEN) {            \
                            sf[0][n][j] = -1e30f; sf[1][n][j] = -1e30f;               \
                        }                                                             \
            }                                                                         \
            union PA { u32 w2[4]; bf16x8 v; } pa[2];                                  \
            _Pragma("unroll")                                                         \
            for (int qq = 0; qq < 2; ++qq) {                                          \
                _Pragma("unroll")                                                     \
                for (int n = 0; n < 2; ++n)                                           \
                    _Pragma("unroll")                                                 \
                    for (int j = 0; j < 4; ++j) sf[qq][n][j] = fexp2(sf[qq][n][j]);   \
                pa[qq].w2[0] = cvtpk_bf16(sf[qq][0][0], sf[qq][0][1]);                \
                pa[qq].w2[1] = cvtpk_bf16(sf[qq][0][2], sf[qq][0][3]);                \
                pa[qq].w2[2] = cvtpk_bf16(sf[qq][1][0], sf[qq][1][1]);                \
                pa[qq].w2[3] = cvtpk_bf16(sf[qq][1][2], sf[qq][1][3]);                \
            }                                                                         \
            __builtin_amdgcn_s_setprio(1);                                            \
            lsum0 = __builtin_amdgcn_mfma_f32_16x16x32_bf16(pa[0].v, ones, lsum0, 0, 0, 0); \
            lsum1 = __builtin_amdgcn_mfma_f32_16x16x32_bf16(pa[1].v, ones, lsum1, 0, 0, 0); \
            _Pragma("unroll")                                                         \
            for (int nd = 0; nd < 4; ++nd) {                                          \
                int byte_ = (h * 64 + fg * 16) ^ ((fr & 7) << 4);                     \
                bf16x8 vf = lds_load8((Vc) + (nd * 16 + fr) * 64 + (byte_ >> 1));     \
                octx[0][nd] = __builtin_amdgcn_mfma_f32_16x16x32_bf16(pa[0].v, vf, octx[0][nd], 0, 0, 0); \
                octx[1][nd] = __builtin_amdgcn_mfma_f32_16x16x32_bf16(pa[1].v, vf, octx[1][nd], 0, 0, 0); \
            }                                                                         \
            __builtin_amdgcn_s_setprio(0);                                            \
        }                                                                             \
    }

__global__ __launch_bounds__(256, 4) void flash(
    const u16* __restrict__ Qh, const u16* __restrict__ Kh, const u16* __restrict__ Vt,
    u16* __restrict__ ctxO)
{
    int wg = (blockIdx.x & 7) * 132 + (blockIdx.x >> 3);   // 1056 % 8 == 0
    int qt = wg % 11, bh = wg / 11;
    int b = bh / NH, h = bh - b * NH;
    int q0 = qt * 128;
    int tid = threadIdx.x, w = tid >> 6, l = tid & 63;
    int fr = l & 15, fg = l >> 4;

    __shared__ u16 Ks0[64 * 64], Ks1[64 * 64];   // 8 KB each
    __shared__ u16 Vs0[64 * 64], Vs1[64 * 64];

    const u16* Qb = Qh + (size_t)bh * S_PAD * 64;
    const u16* Kb = Kh + (size_t)bh * S_PAD * 64;
    const u16* Vb = Vt + (size_t)bh * 64 * S_PAD;

    bf16x8 qf[2][2];
#pragma unroll
    for (int qq = 0; qq < 2; ++qq) {
        int qrow = q0 + w * 32 + qq * 16 + fr;
#pragma unroll
        for (int c = 0; c < 2; ++c)
            qf[qq][c] = as_bf(*(const u16x8*)(Qb + (size_t)qrow * 64 + c * 32 + fg * 8));
    }

    u16x8 ones_u = {0x3F80, 0x3F80, 0x3F80, 0x3F80, 0x3F80, 0x3F80, 0x3F80, 0x3F80};
    bf16x8 ones = as_bf(ones_u);

    f32x4 zero4 = {0.f, 0.f, 0.f, 0.f};
    f32x4 octx[2][4];
#pragma unroll
    for (int qq = 0; qq < 2; ++qq)
#pragma unroll
        for (int nd = 0; nd < 4; ++nd) octx[qq][nd] = zero4;
    f32x4 lsum0 = zero4, lsum1 = zero4;

    // staging: 2 sweeps/tensor (256thr x 16B = 4KB each). 128B rows, ^((r&7)<<4).
    int kfix[2], vfix[2];
#pragma unroll
    for (int i = 0; i < 2; ++i) {
        int sby = (i * 256 + tid) * 16;        // [0, 8192)
        int r = sby >> 7;                      // row 0..63
        int ir = (sby & 127) ^ ((r & 7) << 4); // logical byte in row
        int r5 = r & 31;
        int gk = (r >> 5) * 32 + 8 * ((r5 >> 2) & 3) + 4 * (r5 >> 4) + (r5 & 3);  // per-half g32
        kfix[i] = gk * 64 + (ir >> 1);         // u16 offset into K tile (+k0*64)
        vfix[i] = r * S_PAD + (ir >> 1);       // u16 offset (+k0); row = d
    }

    // prologue: stage tile 0 into buf0
    {
#pragma unroll
        for (int i = 0; i < 2; ++i) {
            gload16((char*)Ks0 + i * 4096 + w * 1024, Kb + kfix[i]);
            gload16((char*)Vs0 + i * 4096 + w * 1024, Vb + vfix[i]);
        }
    }

    // 22 bodies: tiles 0..20 unmasked, tile 21 masked (keys 1344..1407)
    for (int kt = 0; kt < 20; kt += 2) {
        FLASH_B64(Ks0, Vs0, Ks1, Vs1, kt + 1, true, false);
        FLASH_B64(Ks1, Vs1, Ks0, Vs0, kt + 2, true, false);
    }
    FLASH_B64(Ks0, Vs0, Ks1, Vs1, 21, true, false);   // compute 20, stage 21
    FLASH_B64(Ks1, Vs1, Ks0, Vs0, 0, false, true);    // compute 21 (masked)

#pragma unroll
    for (int qq = 0; qq < 2; ++qq)
#pragma unroll
        for (int j = 0; j < 4; ++j) {
            int q = q0 + w * 32 + qq * 16 + fg * 4 + j;
            if (q < S_LEN) {
                float lv = qq ? lsum1[j] : lsum0[j];
                float inv = 1.f / lv;
                size_t rowb = ((size_t)b * S_LEN + q) * HID + h * 64;
#pragma unroll
                for (int nd = 0; nd < 4; ++nd)
                    ctxO[rowb + nd * 16 + fr] = f2bf(octx[qq][nd][j] * inv);
            }
        }
}

// ---------------- launch ----------------

extern "C" void kernel_launch(void* const* d_in, const int* in_sizes, int n_in,
                              void* d_out, int out_size, void* d_ws, size_t ws_size,
                              hipStream_t stream) {
    (void)in_sizes; (void)n_in; (void)out_size; (void)ws_size;
    const float* X  = (const float*)d_in[0];
    const float* SN = (const float*)d_in[1];
    const float* CS = (const float*)d_in[2];
    const float* Wq = (const float*)d_in[3];
    const float* bq = (const float*)d_in[4];
    const float* Wk = (const float*)d_in[5];
    const float* Wv = (const float*)d_in[6];
    const float* bv = (const float*)d_in[7];
    const float* Wp = (const float*)d_in[8];
    const float* bp = (const float*)d_in[9];
    float* OUT = (float*)d_out;
    char* ws = (char*)d_ws;

    u16*   xb   = (u16*)(ws);                    // [11008][768] bf16; later reused as ctx
    u16*   wqkv = (u16*)(ws + 16908288);         // [2304][768] bf16
    u16*   wpb  = (u16*)(ws + 20447232);         // [768][768] bf16
    float* bqkv = (float*)(ws + 21626880);       // [2304] f32
    u16*   Yv   = (u16*)(ws + 21636096);         // [11008][768] bf16 (V only)
    u16*   Qh   = (u16*)(ws + 72360960);         // [96][1408][64] bf16
    u16*   Kh   = (u16*)(ws + 89662464);
    u16*   Vt   = (u16*)(ws + 106963968);        // [96][64][1408] bf16
    u16*   ctx  = xb;

    pack_xw<<<5280, 256, 0, stream>>>(X, Wq, Wk, Wv, Wp, bq, bv, xb, wqkv, wpb, bqkv);
    gemm_qkv256<<<387, 1024, 0, stream>>>(xb, wqkv, bqkv, Qh, Kh, Yv, SN, CS, 768);
    v_pack<<<dim3(22, 96), 256, 0, stream>>>(Yv, Vt);
    flash<<<1056, 256, 0, stream>>>(Qh, Kh, Vt, ctx);
    gemm_proj<<<258, 512, 0, stream>>>(ctx, wpb, bp, OUT, 768, 768, 3, 258);
}

// Round 21
// 165.882 us; speedup vs baseline: 1.0842x; 1.0842x over previous
//
#include <hip/hip_runtime.h>
#include <stdint.h>

typedef unsigned short u16;
typedef unsigned int u32;
typedef u16 u16x8 __attribute__((ext_vector_type(8)));
typedef __bf16 bf16x8 __attribute__((ext_vector_type(8)));
typedef float f32x4 __attribute__((ext_vector_type(4)));

#define S_LEN 1374
#define S_PAD 1408
#define PRE_TOK 5
#define HID 768
#define NH 12
#define MPAD 11008

__device__ __forceinline__ u16 f2bf(float f) {
    union { float f; u32 u; } v; v.f = f;
    u32 r = v.u + 0x7fffu + ((v.u >> 16) & 1u);
    return (u16)(r >> 16);
}
__device__ __forceinline__ bf16x8 as_bf(u16x8 v) { bf16x8 r; __builtin_memcpy(&r, &v, 16); return r; }
__device__ __forceinline__ bf16x8 lds_load8(const u16* p) {
    u16x8 t = *(const u16x8*)p;
    return as_bf(t);
}
__device__ __forceinline__ u32 cvtpk_bf16(float lo, float hi) {
    u32 r;
    asm("v_cvt_pk_bf16_f32 %0, %1, %2" : "=v"(r) : "v"(lo), "v"(hi));
    return r;
}
// raw v_exp_f32: 1 instr. Valid here: inputs in (-1e30, ~+8]; v_exp(-1e30)=0.
__device__ __forceinline__ float fexp2(float x) {
    float r;
    asm("v_exp_f32 %0, %1" : "=v"(r) : "v"(x));
    return r;
}
// async global->LDS, 16B per lane. LDS dest = wave-uniform base + lane*16.
__device__ __forceinline__ void gload16(void* lds, const void* g) {
    unsigned int __attribute__((address_space(1)))* gp =
        (unsigned int __attribute__((address_space(1)))*)(unsigned long long)g;
    unsigned int __attribute__((address_space(3)))* lp =
        (unsigned int __attribute__((address_space(3)))*)(unsigned int)(unsigned long long)lds;
    __builtin_amdgcn_global_load_lds(gp, lp, 16, 0, 0);
}
// bijective XCD-chunk swizzle (m204): contiguous logical spans per XCD.
__device__ __forceinline__ int xcd_swz(int orig, int nwg) {
    int qd = nwg >> 3, rd = nwg & 7;
    int xcd = orig & 7, rem = orig >> 3;
    return (xcd < rd ? xcd * (qd + 1) : rd * (qd + 1) + (xcd - rd) * qd) + rem;
}

// ---------------- fused pack kernel (pack_x + pack_w in one launch) ----------------

__global__ __launch_bounds__(256) void pack_xw(
    const float* __restrict__ X, const float* __restrict__ Wq, const float* __restrict__ Wk,
    const float* __restrict__ Wv, const float* __restrict__ Wp, const float* __restrict__ bq,
    const float* __restrict__ bv, u16* __restrict__ Xb,
    u16* __restrict__ wqkv, u16* __restrict__ wpb, float* __restrict__ bqkv)
{
    int bid = blockIdx.x;
    int tid = threadIdx.x;
    if (bid < 4128) {
        size_t i = (size_t)bid * 256 + tid;
        size_t e = i * 8;
        const size_t TOT = (size_t)10992 * HID;
        u16x8 o = {0,0,0,0,0,0,0,0};
        if (e < TOT) {
            f32x4 a = *(const f32x4*)(X + e);
            f32x4 b = *(const f32x4*)(X + e + 4);
#pragma unroll
            for (int j = 0; j < 4; ++j) { o[j] = f2bf(a[j]); o[4 + j] = f2bf(b[j]); }
        }
        *(u16x8*)(Xb + e) = o;
        return;
    }
    int g = (bid - 4128) * 256 + tid;
    const int QKV8 = 2304 * HID / 8;   // 221184
    const int P8 = HID * HID / 8;      // 73728
    if (g < QKV8) {
        int e = g * 8;
        int row = e / HID, col = e - row * HID;
        const float* src = (row < 768) ? (Wq + (size_t)row * HID + col)
                         : (row < 1536) ? (Wk + (size_t)(row - 768) * HID + col)
                                        : (Wv + (size_t)(row - 1536) * HID + col);
        u16x8 o;
#pragma unroll
        for (int j = 0; j < 8; ++j) o[j] = f2bf(src[j]);
        *(u16x8*)(wqkv + e) = o;
    } else if (g < QKV8 + P8) {
        int e = (g - QKV8) * 8;
        u16x8 o;
#pragma unroll
        for (int j = 0; j < 8; ++j) o[j] = f2bf(Wp[e + j]);
        *(u16x8*)(wpb + e) = o;
    }
    if (g < 288) {
        int e = g * 8;
#pragma unroll
        for (int j = 0; j < 8; ++j) {
            int c = e + j;
            bqkv[c] = (c < 768) ? bq[c] : (c < 1536 ? 0.f : bv[c - 1536]);
        }
    }
}

// ---------------- GEMM (best: 128x256 tile, 8 waves, 2-barrier) ----------------
// EPI=1: f32 out (proj). EPI=2: fused QKV epilogue (Q: bias+RoPE+QSCALE ->
// Qh; K: RoPE -> Kh; V: bias -> Yv).

template <int EPI>
__global__ __launch_bounds__(512) void gemm_nt(
    const u16* __restrict__ A, const u16* __restrict__ B, const float* __restrict__ bias,
    float* __restrict__ Yf, u16* __restrict__ Qh, u16* __restrict__ Kh,
    u16* __restrict__ Yv, const float* __restrict__ SN, const float* __restrict__ CS,
    int N, int K, int nx, int nwg)
{
    __shared__ u16 As[128 * 64];   // 16 KB
    __shared__ u16 Bs[256 * 64];   // 32 KB
    int tid = threadIdx.x;          // 0..511
    int w = tid >> 6, l = tid & 63; // 8 waves
    int fr = l & 15, fg = l >> 4;
    int wg = xcd_swz(blockIdx.x, nwg);
    int col0 = (wg % nx) * 256;
    int row0 = (wg / nx) * 128;
    int wr = (w >> 2) * 64;         // 2 M-waves
    int wc = (w & 3) * 64;          // 4 N-waves

    f32x4 zero4 = {0.f, 0.f, 0.f, 0.f};
    f32x4 acc[4][4];
#pragma unroll
    for (int m = 0; m < 4; ++m)
#pragma unroll
        for (int n = 0; n < 4; ++n) acc[m][n] = zero4;

    int arow[2], aoff[2];           // A: 16 KB = 2 sweeps
#pragma unroll
    for (int i = 0; i < 2; ++i) {
        int sbyte = (i * 512 + tid) * 16;
        int r = sbyte >> 7;
        int ir = (sbyte & 127) ^ ((r & 7) << 4);
        arow[i] = r; aoff[i] = ir >> 1;
    }
    int brow[4], boff[4];           // B: 32 KB = 4 sweeps
#pragma unroll
    for (int i = 0; i < 4; ++i) {
        int sbyte = (i * 512 + tid) * 16;
        int r = sbyte >> 7;
        int ir = (sbyte & 127) ^ ((r & 7) << 4);
        brow[i] = r; boff[i] = ir >> 1;
    }

    for (int kt = 0; kt < K; kt += 64) {
#pragma unroll
        for (int i = 0; i < 2; ++i)
            gload16((char*)As + i * 8192 + w * 1024,
                    A + (size_t)(row0 + arow[i]) * K + kt + aoff[i]);
#pragma unroll
        for (int i = 0; i < 4; ++i)
            gload16((char*)Bs + i * 8192 + w * 1024,
                    B + (size_t)(col0 + brow[i]) * K + kt + boff[i]);
        __syncthreads();
#pragma unroll
        for (int c = 0; c < 2; ++c) {
            bf16x8 af[4], bfr[4];
#pragma unroll
            for (int m = 0; m < 4; ++m) {
                int r = wr + m * 16 + fr;
                int byte_ = (c * 64 + fg * 16) ^ ((r & 7) << 4);
                af[m] = lds_load8(As + r * 64 + (byte_ >> 1));
            }
#pragma unroll
            for (int n = 0; n < 4; ++n) {
                int r = wc + n * 16 + fr;
                int byte_ = (c * 64 + fg * 16) ^ ((r & 7) << 4);
                bfr[n] = lds_load8(Bs + r * 64 + (byte_ >> 1));
            }
#pragma unroll
            for (int m = 0; m < 4; ++m)
#pragma unroll
                for (int n = 0; n < 4; ++n)
                    acc[m][n] = __builtin_amdgcn_mfma_f32_16x16x32_bf16(af[m], bfr[n], acc[m][n], 0, 0, 0);
        }
        __syncthreads();
    }

    if (EPI == 1) {
#pragma unroll
        for (int m = 0; m < 4; ++m)
#pragma unroll
            for (int n = 0; n < 4; ++n) {
                int gn = col0 + wc + n * 16 + fr;
                float bvv = bias[gn];
#pragma unroll
                for (int j = 0; j < 4; ++j) {
                    int gm = row0 + wr + m * 16 + fg * 4 + j;
                    if (gm < 10992) Yf[(size_t)gm * N + gn] = acc[m][n][j] + bvv;
                }
            }
    } else {
        int sect = col0 >= 1536 ? 2 : (col0 >= 768 ? 1 : 0);
        if (sect == 2) {
#pragma unroll
            for (int m = 0; m < 4; ++m)
#pragma unroll
                for (int n = 0; n < 4; ++n) {
                    int gn = col0 + wc + n * 16 + fr;
                    float bvv = bias[gn];
#pragma unroll
                    for (int j = 0; j < 4; ++j) {
                        int gm = row0 + wr + m * 16 + fg * 4 + j;
                        if (gm < 10992)
                            Yv[(size_t)gm * HID + (gn - 1536)] = f2bf(acc[m][n][j] + bvv);
                    }
                }
        } else {
            u16* H = sect ? Kh : Qh;
            const float QS = sect ? 1.f : 0.125f * 1.44269504088896f;   // exp2-domain Q scale
            int hh = ((col0 + wc) >> 6) - sect * NH;                    // head 0..11
            float bv4[4];
#pragma unroll
            for (int n = 0; n < 4; ++n) bv4[n] = bias[col0 + wc + n * 16 + fr];
#pragma unroll
            for (int m = 0; m < 4; ++m)
#pragma unroll
                for (int j = 0; j < 4; ++j) {
                    int gm = row0 + wr + m * 16 + fg * 4 + j;
                    if (gm < 10992) {
                        int b = gm / 1374, s = gm - b * 1374;
                        size_t ob = ((size_t)(b * NH + hh) * S_PAD + s) * 64;
#pragma unroll
                        for (int n2 = 0; n2 < 2; ++n2) {
                            int d = n2 * 16 + fr;
                            float v1 = acc[m][n2][j] + bv4[n2];
                            float v2 = acc[m][n2 + 2][j] + bv4[n2 + 2];
                            float a1 = v1, a2 = v2;
                            if (s >= PRE_TOK) {
                                size_t rr = (size_t)(s - PRE_TOK) * 64;
                                float c1 = CS[rr + d], s1 = SN[rr + d];
                                float c2 = CS[rr + d + 32], s2 = SN[rr + d + 32];
                                a1 = v1 * c1 - v2 * s1;
                                a2 = v2 * c2 + v1 * s2;
                            }
                            H[ob + d]      = f2bf(a1 * QS);
                            H[ob + d + 32] = f2bf(a2 * QS);
                        }
                    }
                }
        }
    }
}

// ---------------- V head-transpose: Yv[token][768] -> Vt[bh][64][S_PAD] ----------------

__global__ __launch_bounds__(256) void v_pack(const u16* __restrict__ Yv, u16* __restrict__ Vt) {
    int st = blockIdx.x, bh = blockIdx.y;
    int b = bh / NH, h = bh - b * NH;
    int tid = threadIdx.x;
    int sl = tid >> 2, dg = (tid & 3) * 8;
    int s = st * 64 + sl;
    __shared__ u16 vtile[64 * 64];

    u16x8 a = {0,0,0,0,0,0,0,0}, a2 = {0,0,0,0,0,0,0,0};
    if (s < S_LEN) {
        size_t base = ((size_t)b * S_LEN + s) * HID + h * 64;
        a  = *(const u16x8*)(Yv + base + dg);
        a2 = *(const u16x8*)(Yv + base + 32 + dg);
    }
#pragma unroll
    for (int j = 0; j < 8; ++j) {
        vtile[(dg + j) * 64 + sl] = a[j];
        vtile[(32 + dg + j) * 64 + sl] = a2[j];
    }
    __syncthreads();
    int d = tid >> 2, so = (tid & 3) * 8;
    u16x8 ov0 = *(const u16x8*)(vtile + d * 64 + so);
    u16x8 ov1 = *(const u16x8*)(vtile + d * 64 + so + 32);
    size_t vrow = ((size_t)bh * 64 + d) * S_PAD + st * 64;
    *(u16x8*)(Vt + vrow + so) = ov0;
    *(u16x8*)(Vt + vrow + so + 32) = ov1;
}

// ---------------- flash attention (KVBLK=64, two 32-key sub-phases/barrier) ----

#define FLASH_B64(Kc, Vc, KsN, VsN, ktn, DO_STAGE, DO_MASK)                           \
    {                                                                                 \
        asm volatile("s_waitcnt vmcnt(0) lgkmcnt(0)" ::: "memory");                   \
        __syncthreads();                                                              \
        if (DO_STAGE) {                                                               \
            int k0n = (ktn) * 64;                                                     \
            _Pragma("unroll")                                                         \
            for (int i = 0; i < 2; ++i) {                                             \
                gload16((char*)(KsN) + i * 4096 + w * 1024, Kb + (size_t)k0n * 64 + kfix[i]); \
                gload16((char*)(VsN) + i * 4096 + w * 1024, Vb + (size_t)k0n + vfix[i]);      \
            }                                                                         \
        }                                                                             \
        _Pragma("unroll")                                                             \
        for (int h = 0; h < 2; ++h) {                                                 \
            f32x4 sf[2][2];                                                           \
            __builtin_amdgcn_s_setprio(1);                                            \
            _Pragma("unroll")                                                         \
            for (int n = 0; n < 2; ++n) {                                             \
                f32x4 q0a = zero4, q1a = zero4;                                       \
                _Pragma("unroll")                                                     \
                for (int c = 0; c < 2; ++c) {                                         \
                    int byte_ = (c * 64 + fg * 16) ^ ((fr & 7) << 4);                 \
                    bf16x8 kf = lds_load8((Kc) + (h * 32 + n * 16 + fr) * 64 + (byte_ >> 1)); \
                    q0a = __builtin_amdgcn_mfma_f32_16x16x32_bf16(kf, qf[0][c], q0a, 0, 0, 0); \
                    q1a = __builtin_amdgcn_mfma_f32_16x16x32_bf16(kf, qf[1][c], q1a, 0, 0, 0); \
                }                                                                     \
                sf[0][n] = q0a; sf[1][n] = q1a;                                       \
            }                                                                         \
            __builtin_amdgcn_s_setprio(0);                                            \
            if (DO_MASK) {                                                            \
                _Pragma("unroll")                                                     \
                for (int n = 0; n < 2; ++n)                                           \
                    _Pragma("unroll")                                                 \
                    for (int j = 0; j < 4; ++j)                                       \
                        if (1344 + h * 32 + 8 * fg + 4 * n + j >= S_LEN) {            \
                            sf[0][n][j] = -1e30f; sf[1][n][j] = -1e30f;               \
                        }                                                             \
            }                                                                         \
            union PA { u32 w2[4]; bf16x8 v; } pa[2];                                  \
            _Pragma("unroll")                                                         \
            for (int qq = 0; qq < 2; ++qq) {                                          \
                _Pragma("unroll")                                                     \
                for (int n = 0; n < 2; ++n)                                           \
                    _Pragma("unroll")                                                 \
                    for (int j = 0; j < 4; ++j) sf[qq][n][j] = fexp2(sf[qq][n][j]);   \
                pa[qq].w2[0] = cvtpk_bf16(sf[qq][0][0], sf[qq][0][1]);                \
                pa[qq].w2[1] = cvtpk_bf16(sf[qq][0][2], sf[qq][0][3]);                \
                pa[qq].w2[2] = cvtpk_bf16(sf[qq][1][0], sf[qq][1][1]);                \
                pa[qq].w2[3] = cvtpk_bf16(sf[qq][1][2], sf[qq][1][3]);                \
            }                                                                         \
            __builtin_amdgcn_s_setprio(1);                                            \
            lsum0 = __builtin_amdgcn_mfma_f32_16x16x32_bf16(pa[0].v, ones, lsum0, 0, 0, 0); \
            lsum1 = __builtin_amdgcn_mfma_f32_16x16x32_bf16(pa[1].v, ones, lsum1, 0, 0, 0); \
            _Pragma("unroll")                                                         \
            for (int nd = 0; nd < 4; ++nd) {                                          \
                int byte_ = (h * 64 + fg * 16) ^ ((fr & 7) << 4);                     \
                bf16x8 vf = lds_load8((Vc) + (nd * 16 + fr) * 64 + (byte_ >> 1));     \
                octx[0][nd] = __builtin_amdgcn_mfma_f32_16x16x32_bf16(pa[0].v, vf, octx[0][nd], 0, 0, 0); \
                octx[1][nd] = __builtin_amdgcn_mfma_f32_16x16x32_bf16(pa[1].v, vf, octx[1][nd], 0, 0, 0); \
            }                                                                         \
            __builtin_amdgcn_s_setprio(0);                                            \
        }                                                                             \
    }

__global__ __launch_bounds__(256, 4) void flash(
    const u16* __restrict__ Qh, const u16* __restrict__ Kh, const u16* __restrict__ Vt,
    u16* __restrict__ ctxO)
{
    int wg = (blockIdx.x & 7) * 132 + (blockIdx.x >> 3);   // 1056 % 8 == 0
    int qt = wg % 11, bh = wg / 11;
    int b = bh / NH, h = bh - b * NH;
    int q0 = qt * 128;
    int tid = threadIdx.x, w = tid >> 6, l = tid & 63;
    int fr = l & 15, fg = l >> 4;

    __shared__ u16 Ks0[64 * 64], Ks1[64 * 64];   // 8 KB each
    __shared__ u16 Vs0[64 * 64], Vs1[64 * 64];

    const u16* Qb = Qh + (size_t)bh * S_PAD * 64;
    const u16* Kb = Kh + (size_t)bh * S_PAD * 64;
    const u16* Vb = Vt + (size_t)bh * 64 * S_PAD;

    bf16x8 qf[2][2];
#pragma unroll
    for (int qq = 0; qq < 2; ++qq) {
        int qrow = q0 + w * 32 + qq * 16 + fr;
#pragma unroll
        for (int c = 0; c < 2; ++c)
            qf[qq][c] = as_bf(*(const u16x8*)(Qb + (size_t)qrow * 64 + c * 32 + fg * 8));
    }

    u16x8 ones_u = {0x3F80, 0x3F80, 0x3F80, 0x3F80, 0x3F80, 0x3F80, 0x3F80, 0x3F80};
    bf16x8 ones = as_bf(ones_u);

    f32x4 zero4 = {0.f, 0.f, 0.f, 0.f};
    f32x4 octx[2][4];
#pragma unroll
    for (int qq = 0; qq < 2; ++qq)
#pragma unroll
        for (int nd = 0; nd < 4; ++nd) octx[qq][nd] = zero4;
    f32x4 lsum0 = zero4, lsum1 = zero4;

    // staging: 2 sweeps/tensor (256thr x 16B = 4KB each). 128B rows, ^((r&7)<<4).
    int kfix[2], vfix[2];
#pragma unroll
    for (int i = 0; i < 2; ++i) {
        int sby = (i * 256 + tid) * 16;        // [0, 8192)
        int r = sby >> 7;                      // row 0..63
        int ir = (sby & 127) ^ ((r & 7) << 4); // logical byte in row
        int r5 = r & 31;
        int gk = (r >> 5) * 32 + 8 * ((r5 >> 2) & 3) + 4 * (r5 >> 4) + (r5 & 3);  // per-half g32
        kfix[i] = gk * 64 + (ir >> 1);         // u16 offset into K tile (+k0*64)
        vfix[i] = r * S_PAD + (ir >> 1);       // u16 offset (+k0); row = d
    }

    // prologue: stage tile 0 into buf0
    {
#pragma unroll
        for (int i = 0; i < 2; ++i) {
            gload16((char*)Ks0 + i * 4096 + w * 1024, Kb + kfix[i]);
            gload16((char*)Vs0 + i * 4096 + w * 1024, Vb + vfix[i]);
        }
    }

    // 22 bodies: tiles 0..20 unmasked, tile 21 masked (keys 1344..1407)
    for (int kt = 0; kt < 20; kt += 2) {
        FLASH_B64(Ks0, Vs0, Ks1, Vs1, kt + 1, true, false);
        FLASH_B64(Ks1, Vs1, Ks0, Vs0, kt + 2, true, false);
    }
    FLASH_B64(Ks0, Vs0, Ks1, Vs1, 21, true, false);   // compute 20, stage 21
    FLASH_B64(Ks1, Vs1, Ks0, Vs0, 0, false, true);    // compute 21 (masked)

#pragma unroll
    for (int qq = 0; qq < 2; ++qq)
#pragma unroll
        for (int j = 0; j < 4; ++j) {
            int q = q0 + w * 32 + qq * 16 + fg * 4 + j;
            if (q < S_LEN) {
                float lv = qq ? lsum1[j] : lsum0[j];
                float inv = 1.f / lv;
                size_t rowb = ((size_t)b * S_LEN + q) * HID + h * 64;
#pragma unroll
                for (int nd = 0; nd < 4; ++nd)
                    ctxO[rowb + nd * 16 + fr] = f2bf(octx[qq][nd][j] * inv);
            }
        }
}

// ---------------- launch ----------------

extern "C" void kernel_launch(void* const* d_in, const int* in_sizes, int n_in,
                              void* d_out, int out_size, void* d_ws, size_t ws_size,
                              hipStream_t stream) {
    (void)in_sizes; (void)n_in; (void)out_size; (void)ws_size;
    const float* X  = (const float*)d_in[0];
    const float* SN = (const float*)d_in[1];
    const float* CS = (const float*)d_in[2];
    const float* Wq = (const float*)d_in[3];
    const float* bq = (const float*)d_in[4];
    const float* Wk = (const float*)d_in[5];
    const float* Wv = (const float*)d_in[6];
    const float* bv = (const float*)d_in[7];
    const float* Wp = (const float*)d_in[8];
    const float* bp = (const float*)d_in[9];
    float* OUT = (float*)d_out;
    char* ws = (char*)d_ws;

    u16*   xb   = (u16*)(ws);                    // [11008][768] bf16; later reused as ctx
    u16*   wqkv = (u16*)(ws + 16908288);         // [2304][768] bf16
    u16*   wpb  = (u16*)(ws + 20447232);         // [768][768] bf16
    float* bqkv = (float*)(ws + 21626880);       // [2304] f32
    u16*   Yv   = (u16*)(ws + 21636096);         // [11008][768] bf16 (V only)
    u16*   Qh   = (u16*)(ws + 72360960);         // [96][1408][64] bf16
    u16*   Kh   = (u16*)(ws + 89662464);
    u16*   Vt   = (u16*)(ws + 106963968);        // [96][64][1408] bf16
    u16*   ctx  = xb;

    pack_xw<<<5280, 256, 0, stream>>>(X, Wq, Wk, Wv, Wp, bq, bv, xb, wqkv, wpb, bqkv);
    gemm_nt<2><<<774, 512, 0, stream>>>(xb, wqkv, bqkv, nullptr, Qh, Kh, Yv, SN, CS, 2304, 768, 9, 774);
    v_pack<<<dim3(22, 96), 256, 0, stream>>>(Yv, Vt);
    flash<<<1056, 256, 0, stream>>>(Qh, Kh, Vt, ctx);
    gemm_nt<1><<<258, 512, 0, stream>>>(ctx, wpb, bp, OUT, nullptr, nullptr, nullptr, nullptr, nullptr, 768, 768, 3, 258);
}